// Round 10
// baseline (653.526 us; speedup 1.0000x reference)
//
#include <hip/hip_runtime.h>
#include <math.h>

constexpr int D_TOT = 97;
constexpr int K_POOL = 30;
constexpr int BSHIFT = 10;                 // 1024 nodes per bucket
constexpr int BSIZE  = 1 << BSHIFT;
constexpr int MAXB   = 256;                // max buckets (n < 262144)

// ---------------- bucket histogram (LDS-aggregated, int4 loads) ----------------
__global__ __launch_bounds__(256) void k_bcount(const int* __restrict__ dst, int E,
                                                int* __restrict__ bucketcnt, int B) {
    __shared__ int h[MAXB];
    int t = threadIdx.x;
    for (int i = t; i < MAXB; i += 256) h[i] = 0;
    __syncthreads();
    int e0 = blockIdx.x * 4096;
    int cnt = min(4096, E - e0);
    if (cnt == 4096) {
        const int4* d4 = (const int4*)(dst + e0);
        for (int i = t; i < 1024; i += 256) {
            int4 v = d4[i];
            atomicAdd(&h[v.x >> BSHIFT], 1);
            atomicAdd(&h[v.y >> BSHIFT], 1);
            atomicAdd(&h[v.z >> BSHIFT], 1);
            atomicAdd(&h[v.w >> BSHIFT], 1);
        }
    } else {
        for (int i = t; i < cnt; i += 256)
            atomicAdd(&h[dst[e0 + i] >> BSHIFT], 1);
    }
    __syncthreads();
    for (int i = t; i < B; i += 256)
        if (h[i]) atomicAdd(&bucketcnt[i], h[i]);
}

// ---------------- bucket exclusive scan (block 0) + per-graph starts (blocks 1..) ----------------
__global__ void k_bscan_starts(const int* __restrict__ cnt, int* __restrict__ bstart,
                               int* __restrict__ bcursor, int B, int E,
                               const int* __restrict__ batch, int n, int G,
                               int* __restrict__ starts) {
    int t = threadIdx.x;          // blockDim = 256
    if (blockIdx.x == 0) {
        __shared__ int s[MAXB];
        int mine = (t < B) ? cnt[t] : 0;
        s[t] = mine;
        __syncthreads();
        for (int off = 1; off < MAXB; off <<= 1) {
            int add = (t >= off) ? s[t - off] : 0;
            __syncthreads();
            s[t] += add;
            __syncthreads();
        }
        if (t < B) { int ex = s[t] - mine; bstart[t] = ex; bcursor[t] = ex; }
        if (t == 0) bstart[B] = E;
    } else {
        int g = (blockIdx.x - 1) * 256 + t;
        if (g > G) return;
        if (g == G) { starts[G] = n; return; }
        int lo = 0, hi = n;
        while (lo < hi) { int mid = (lo + hi) >> 1; if (batch[mid] < g) lo = mid + 1; else hi = mid; }
        starts[g] = lo;
    }
}

// ---------------- phase 1: partition edges into bucket-contiguous packed array ----------------
__global__ __launch_bounds__(256) void k_part(const int* __restrict__ src,
                                              const int* __restrict__ dst, int E, int B,
                                              int* __restrict__ bcursor,
                                              unsigned* __restrict__ bpk) {
    __shared__ int4 s_src4[1024];
    __shared__ int4 s_dst4[1024];
    __shared__ int hist[MAXB];
    __shared__ int base[MAXB];
    int* s_src = (int*)s_src4;
    int* s_dst = (int*)s_dst4;
    int t = threadIdx.x;
    int e0 = blockIdx.x * 4096;
    int cnt = min(4096, E - e0);
    for (int i = t; i < MAXB; i += 256) hist[i] = 0;
    __syncthreads();
    if (cnt == 4096) {
        const int4* sv4 = (const int4*)(src + e0);
        const int4* dv4 = (const int4*)(dst + e0);
        for (int i = t; i < 1024; i += 256) {
            int4 a = sv4[i];
            int4 b = dv4[i];
            s_src4[i] = a;
            s_dst4[i] = b;
            atomicAdd(&hist[b.x >> BSHIFT], 1);
            atomicAdd(&hist[b.y >> BSHIFT], 1);
            atomicAdd(&hist[b.z >> BSHIFT], 1);
            atomicAdd(&hist[b.w >> BSHIFT], 1);
        }
    } else {
        for (int i = t; i < cnt; i += 256) {
            int d = dst[e0 + i];
            s_src[i] = src[e0 + i];
            s_dst[i] = d;
            atomicAdd(&hist[d >> BSHIFT], 1);
        }
    }
    __syncthreads();
    for (int i = t; i < B; i += 256) {
        int hh = hist[i];
        base[i] = hh ? atomicAdd(&bcursor[i], hh) : 0;
        hist[i] = 0;
    }
    __syncthreads();
    for (int i = t; i < cnt; i += 256) {
        int d = s_dst[i];
        int b = d >> BSHIFT;
        int off = atomicAdd(&hist[b], 1);
        bpk[base[b] + off] = ((unsigned)(d & (BSIZE - 1)) << 18) | (unsigned)s_src[i];
    }
}

// ---------------- phase 2: per-bucket CSR fill (512 thr) ----------------
__global__ __launch_bounds__(512) void k_fill3(const unsigned* __restrict__ bpk,
                                               const int* __restrict__ bstart,
                                               int n, int B,
                                               int* __restrict__ deg,
                                               int* __restrict__ rowstart,
                                               float* __restrict__ dis,
                                               int* __restrict__ ssrc) {
    __shared__ int cnt[BSIZE];
    __shared__ int s512[512];
    int b = blockIdx.x;
    int t = threadIdx.x;
    int s0 = bstart[b], s1 = bstart[b + 1];

    for (int i = t; i < BSIZE; i += 512) cnt[i] = 0;
    __syncthreads();
    for (int i = s0 + t; i < s1; i += 512)
        atomicAdd(&cnt[bpk[i] >> 18], 1);
    __syncthreads();

    int c0 = cnt[2 * t], c1 = cnt[2 * t + 1];
    int tot = c0 + c1;
    s512[t] = tot;
    __syncthreads();
    for (int off = 1; off < 512; off <<= 1) {
        int add = (t >= off) ? s512[t - off] : 0;
        __syncthreads();
        s512[t] += add;
        __syncthreads();
    }
    int g0 = s0 + s512[t] - tot;
    int p0 = g0, p1 = g0 + c0;

    float d0 = rsqrtf((float)(c0 + 1)), d1 = rsqrtf((float)(c1 + 1));

    int node0 = (b << BSHIFT) + 2 * t;
    if (node0 + 0 < n) { rowstart[node0 + 0] = p0; deg[node0 + 0] = c0; dis[node0 + 0] = d0; }
    if (node0 + 1 < n) { rowstart[node0 + 1] = p1; deg[node0 + 1] = c1; dis[node0 + 1] = d1; }

    cnt[2 * t] = p0; cnt[2 * t + 1] = p1;
    __syncthreads();

    for (int i = s0 + t; i < s1; i += 512) {
        unsigned pk = bpk[i];
        int pos = atomicAdd(&cnt[pk >> 18], 1);
        ssrc[pos] = (int)(pk & 0x3FFFFu);
    }
}

// ---------------- layer-0 transform into slab layout: slab[p*n+i] = dis[i]*(x[i,:20] @ W0[:,4p..4p+4)) ----------------
__global__ void k_t0(const float* __restrict__ x,
                     const float* __restrict__ W0,
                     const float* __restrict__ dis,
                     float4* __restrict__ slab, int n) {
    int t = blockIdx.x * blockDim.x + threadIdx.x;
    if (t >= n * 8) return;
    int p = t / n, i = t - p * n;
    const float* xr = x + (size_t)i * 20;
    int c0 = p * 4;
    float a0 = 0.f, a1 = 0.f, a2 = 0.f, a3 = 0.f;
#pragma unroll
    for (int f = 0; f < 20; ++f) {
        float xv = xr[f];
        const float* wr = &W0[f * 32 + c0];
        a0 += xv * wr[0];
        a1 += xv * wr[1];
        a2 += xv * wr[2];
        a3 += xv * wr[3];
    }
    float sc = dis[i];
    slab[t] = make_float4(sc * a0, sc * a1, sc * a2, sc * a3);
}

// ---------------- XCD-sliced CSR gather: one block handles one 16-B slice for 256 nodes ----------------
// slice = blockIdx & 7 -> with round-robin block->XCD dispatch, slab p (2.4 MB) stays resident in XCD p's L2
__global__ __launch_bounds__(256) void k_gatherT(
    const int* __restrict__ rowstart, const int* __restrict__ deg,
    const int* __restrict__ ssrc, const float4* __restrict__ slab,
    const float* __restrict__ dis, const float* __restrict__ bias,
    float* __restrict__ feat, int off, int n)
{
    int slice = blockIdx.x & 7;
    int i = (blockIdx.x >> 3) * 256 + threadIdx.x;
    if (i >= n) return;
    const float4* sl = slab + (size_t)slice * n;
    int r0 = rowstart[i], d = deg[i];
    float4 acc = sl[i];                    // self-loop term
    int j = 0;
    for (; j + 4 <= d; j += 4) {
        int s0 = ssrc[r0 + j + 0];
        int s1 = ssrc[r0 + j + 1];
        int s2 = ssrc[r0 + j + 2];
        int s3 = ssrc[r0 + j + 3];
        float4 v0 = sl[s0];
        float4 v1 = sl[s1];
        float4 v2 = sl[s2];
        float4 v3 = sl[s3];
        acc.x += (v0.x + v1.x) + (v2.x + v3.x);
        acc.y += (v0.y + v1.y) + (v2.y + v3.y);
        acc.z += (v0.z + v1.z) + (v2.z + v3.z);
        acc.w += (v0.w + v1.w) + (v2.w + v3.w);
    }
    for (; j < d; ++j) {
        float4 v = sl[ssrc[r0 + j]];
        acc.x += v.x; acc.y += v.y; acc.z += v.z; acc.w += v.w;
    }
    float sc = dis[i];
    float* fr = feat + (size_t)i * D_TOT + off + slice * 4;
    fr[0] = tanhf(sc * acc.x + bias[slice * 4 + 0]);
    fr[1] = tanhf(sc * acc.y + bias[slice * 4 + 1]);
    fr[2] = tanhf(sc * acc.z + bias[slice * 4 + 2]);
    fr[3] = tanhf(sc * acc.w + bias[slice * 4 + 3]);
}

// ---------------- transform feat cols [off,off+32) -> next slab (MODE 0) or scalar g1 (MODE 1) ----------------
template<int MODE>
__global__ __launch_bounds__(256) void k_trans(
    const float* __restrict__ feat, int off,
    const float* __restrict__ dis, const float* __restrict__ Wn,
    float4* __restrict__ slabNext, float* __restrict__ g1, int n)
{
    __shared__ float hs[32][33];
    __shared__ float wsm[32 * 32];
    int base = blockIdx.x * 32;
    int tid = threadIdx.x;

    if (MODE == 0) {
        for (int q = tid; q < 1024; q += 256) wsm[q] = Wn[q];
    }
    for (int q = tid; q < 1024; q += 256) {
        int il = q >> 5, c = q & 31;
        int i = base + il;
        hs[il][c] = (i < n) ? feat[(size_t)i * D_TOT + off + c] : 0.f;
    }
    __syncthreads();

    if (MODE == 0) {
        int p = tid >> 5, il = tid & 31;
        int i = base + il;
        if (i < n) {
            const float* hr = hs[il];
            int c0 = p * 4;
            float a0 = 0.f, a1 = 0.f, a2 = 0.f, a3 = 0.f;
#pragma unroll
            for (int f = 0; f < 32; ++f) {
                float hv = hr[f];
                const float* wr = &wsm[f * 32 + c0];
                a0 += hv * wr[0];
                a1 += hv * wr[1];
                a2 += hv * wr[2];
                a3 += hv * wr[3];
            }
            float sc = dis[i];
            slabNext[(size_t)p * n + i] = make_float4(sc * a0, sc * a1, sc * a2, sc * a3);
        }
    } else {
        if (tid < 32) {
            int i = base + tid;
            if (i < n) {
                const float* hr = hs[tid];
                float a = 0.f;
#pragma unroll
                for (int f = 0; f < 32; ++f) a += hr[f] * Wn[f];
                g1[i] = dis[i] * a;
            }
        }
    }
}

// ---------------- fused layer-3 gather + sort-pool (bitonic) + CNN + MLP ----------------
constexpr int SORTN = 512;

__global__ __launch_bounds__(256) void k_cnn(
    const float* __restrict__ feat,
    const int* __restrict__ starts,
    const int* __restrict__ rowstart, const int* __restrict__ deg,
    const int* __restrict__ ssrc, const float* __restrict__ g1,
    const float* __restrict__ dis, const float* __restrict__ b3,
    const float* __restrict__ c1w, const float* __restrict__ c1b,
    const float* __restrict__ c2w, const float* __restrict__ c2b,
    const float* __restrict__ m1w, const float* __restrict__ m1b,
    const float* __restrict__ m2w, const float* __restrict__ m2b,
    float* __restrict__ out)
{
    int g = blockIdx.x;
    int tid = threadIdx.x;   // 256

    __shared__ unsigned long long keys[SORTN];
    __shared__ float vals[SORTN];
    __shared__ float pooled[K_POOL][D_TOT];
    __shared__ float y[16][K_POOL];
    __shared__ float z[16][15];
    __shared__ float u[352];
    __shared__ float pm[256];
    __shared__ float hid[32];

    int start = starts[g];
    int cnt = starts[g + 1] - start;
    if (cnt > SORTN) cnt = SORTN;
    int kk = cnt < K_POOL ? cnt : K_POOL;
    float bias3 = b3[0];

    for (int il = tid; il < cnt; il += 256) {
        int i = start + il;
        int r0 = rowstart[i], d = deg[i];
        float acc = g1[i];
        for (int j = 0; j < d; ++j) acc += g1[ssrc[r0 + j]];
        vals[il] = tanhf(dis[i] * acc + bias3);
    }
    __syncthreads();

    int SN = (cnt <= 256) ? 256 : SORTN;

    for (int i = tid; i < SN; i += 256) {
        unsigned long long kv;
        if (i < cnt) {
            float v = vals[i];
            unsigned uo = __float_as_uint(v);
            uo ^= (unsigned)((int)uo >> 31) | 0x80000000u;
            kv = ((unsigned long long)(~uo) << 32) | (unsigned)i;
        } else {
            kv = 0xFFFFFFFFFFFFFFFFull;
        }
        keys[i] = kv;
    }
    __syncthreads();

    for (int sz = 2; sz <= SN; sz <<= 1) {
        for (int j = sz >> 1; j > 0; j >>= 1) {
            for (int q = tid; q < SN; q += 256) {
                int l = q ^ j;
                if (l > q) {
                    bool asc = ((q & sz) == 0);
                    unsigned long long a = keys[q], bb = keys[l];
                    if ((a > bb) == asc) { keys[q] = bb; keys[l] = a; }
                }
            }
            __syncthreads();
        }
    }

    float* pf = &pooled[0][0];
    for (int t = tid; t < K_POOL * D_TOT; t += 256) pf[t] = 0.f;
    __syncthreads();
    for (int t = tid; t < kk * 96; t += 256) {
        int r = t / 96, c = t - r * 96;
        int idx = (int)(keys[r] & 0xFFFFFFFFull);
        pooled[r][c] = feat[(size_t)(start + idx) * D_TOT + c];
    }
    for (int r = tid; r < kk; r += 256) {
        int idx = (int)(keys[r] & 0xFFFFFFFFull);
        pooled[r][96] = vals[idx];
    }
    __syncthreads();

    for (int t = tid; t < 16 * K_POOL; t += 256) {
        int o = t / K_POOL, p = t - o * K_POOL;
        float a = c1b[o];
        const float* w = c1w + o * D_TOT;
        const float* pr = &pooled[p][0];
#pragma unroll 1
        for (int c = 0; c < D_TOT; ++c) a += pr[c] * w[c];
        y[o][p] = fmaxf(a, 0.f);
    }
    __syncthreads();

    for (int t = tid; t < 16 * 15; t += 256) {
        int o = t / 15, p = t - o * 15;
        z[o][p] = fmaxf(y[o][2 * p], y[o][2 * p + 1]);
    }
    __syncthreads();

    for (int t = tid; t < 32 * 11; t += 256) {
        int q = t / 11, p = t - q * 11;
        float a = c2b[q];
        const float* w = c2w + q * 16 * 5;
#pragma unroll 1
        for (int c = 0; c < 16; ++c) {
#pragma unroll
            for (int j = 0; j < 5; ++j) a += z[c][p + j] * w[c * 5 + j];
        }
        u[t] = fmaxf(a, 0.f);
    }
    __syncthreads();

    {
        int grp = tid >> 5, o = tid & 31;
        float a = 0.f;
        int i0 = grp * 44;
#pragma unroll 1
        for (int i = i0; i < i0 + 44; ++i) a += u[i] * m1w[i * 32 + o];
        pm[tid] = a;
    }
    __syncthreads();
    if (tid < 32) {
        float a = m1b[tid];
#pragma unroll
        for (int gg = 0; gg < 8; ++gg) a += pm[tid + 32 * gg];
        hid[tid] = fmaxf(a, 0.f);
    }
    __syncthreads();

    if (tid == 0) {
        float a = m2b[0];
#pragma unroll
        for (int m = 0; m < 32; ++m) a += hid[m] * m2w[m];
        out[g] = a;
    }
}

// ---------------- launch ----------------
extern "C" void kernel_launch(void* const* d_in, const int* in_sizes, int n_in,
                              void* d_out, int out_size, void* d_ws, size_t ws_size,
                              hipStream_t stream) {
    const float* x    = (const float*)d_in[0];
    const int*   ei   = (const int*)d_in[1];
    const int*   batch= (const int*)d_in[2];
    const float* W0   = (const float*)d_in[3];
    const float* b0   = (const float*)d_in[4];
    const float* W1   = (const float*)d_in[5];
    const float* b1   = (const float*)d_in[6];
    const float* W2   = (const float*)d_in[7];
    const float* b2   = (const float*)d_in[8];
    const float* W3   = (const float*)d_in[9];
    const float* b3   = (const float*)d_in[10];
    const float* c1w  = (const float*)d_in[11];
    const float* c1b  = (const float*)d_in[12];
    const float* c2w  = (const float*)d_in[13];
    const float* c2b  = (const float*)d_in[14];
    const float* m1w  = (const float*)d_in[15];
    const float* m1b  = (const float*)d_in[16];
    const float* m2w  = (const float*)d_in[17];
    const float* m2b  = (const float*)d_in[18];

    const int n = in_sizes[0] / 20;
    const int E = in_sizes[1] / 2;
    const int G = out_size;
    const int* srcv = ei;
    const int* dstv = ei + E;
    const int B = (n + BSIZE - 1) >> BSHIFT;
    const int nE4 = (E + 4095) / 4096;

    char* ws = (char*)d_ws;
    float* feat    = (float*)ws;  ws += (size_t)n * D_TOT * sizeof(float);
    float* slabA   = (float*)ws;  ws += (size_t)n * 32 * sizeof(float);
    float* slabB   = (float*)ws;  ws += (size_t)n * 32 * sizeof(float);
    int*   ssrc    = (int*)ws;    ws += (size_t)E * sizeof(int);
    unsigned* bpk  = (unsigned*)ws; ws += (size_t)E * sizeof(unsigned);
    int*   rowstart= (int*)ws;    ws += (size_t)n * sizeof(int);
    int*   deg     = (int*)ws;    ws += (size_t)n * sizeof(int);
    float* dis     = (float*)ws;  ws += (size_t)n * sizeof(float);
    int*   startsb = (int*)ws;    ws += (size_t)(G + 1) * sizeof(int);
    int*   bucketcnt=(int*)ws;    ws += (size_t)MAXB * sizeof(int);
    int*   bstart  = (int*)ws;    ws += (size_t)(MAXB + 1) * sizeof(int);
    int*   bcursor = (int*)ws;    ws += (size_t)MAXB * sizeof(int);
    float* g1      = (float*)bpk;  // alias: bpk dead after CSR build

    hipMemsetAsync(bucketcnt, 0, (size_t)MAXB * sizeof(int), stream);

    // CSR build (bucketed, no global data atomics; reused by all 4 layers)
    k_bcount<<<nE4, 256, 0, stream>>>(dstv, E, bucketcnt, B);
    const int nSB = (G + 1 + 255) / 256;
    k_bscan_starts<<<1 + nSB, 256, 0, stream>>>(bucketcnt, bstart, bcursor, B, E,
                                                batch, n, G, startsb);
    k_part<<<nE4, 256, 0, stream>>>(srcv, dstv, E, B, bcursor, bpk);
    k_fill3<<<B, 512, 0, stream>>>(bpk, bstart, n, B, deg, rowstart, dis, ssrc);

    // layer-0 transform into slab layout (needs dis)
    k_t0<<<(n * 8 + 255) / 256, 256, 0, stream>>>(x, W0, dis, (float4*)slabA, n);

    const int nchunk = (n + 255) / 256;
    const int gridT = nchunk * 8;
    const int ntr = (n + 31) / 32;
    // layer 0 gather (sliced) -> feat[:,0:32); transform W1 -> slabB
    k_gatherT<<<gridT, 256, 0, stream>>>(rowstart, deg, ssrc, (const float4*)slabA, dis, b0, feat, 0, n);
    k_trans<0><<<ntr, 256, 0, stream>>>(feat, 0, dis, W1, (float4*)slabB, nullptr, n);
    // layer 1
    k_gatherT<<<gridT, 256, 0, stream>>>(rowstart, deg, ssrc, (const float4*)slabB, dis, b1, feat, 32, n);
    k_trans<0><<<ntr, 256, 0, stream>>>(feat, 32, dis, W2, (float4*)slabA, nullptr, n);
    // layer 2
    k_gatherT<<<gridT, 256, 0, stream>>>(rowstart, deg, ssrc, (const float4*)slabA, dis, b2, feat, 64, n);
    k_trans<1><<<ntr, 256, 0, stream>>>(feat, 64, dis, W3, nullptr, g1, n);

    // fused layer-3 gather + sort-pool + CNN + MLP
    k_cnn<<<G, 256, 0, stream>>>(feat, startsb, rowstart, deg, ssrc, g1, dis, b3,
                                 c1w, c1b, c2w, c2b, m1w, m1b, m2w, m2b,
                                 (float*)d_out);
}

// Round 11
// 441.354 us; speedup vs baseline: 1.4807x; 1.4807x over previous
//
#include <hip/hip_runtime.h>
#include <math.h>

constexpr int D_TOT = 97;
constexpr int K_POOL = 30;
constexpr int BSHIFT = 9;                  // 512 nodes per bucket
constexpr int BSIZE  = 1 << BSHIFT;
constexpr int MAXB   = 512;                // max buckets (n < 262144)

// ---------------- bucket histogram (LDS-aggregated, int4 loads) ----------------
__global__ __launch_bounds__(256) void k_bcount(const int* __restrict__ dst, int E,
                                                int* __restrict__ bucketcnt, int B) {
    __shared__ int h[MAXB];
    int t = threadIdx.x;
    for (int i = t; i < MAXB; i += 256) h[i] = 0;
    __syncthreads();
    int e0 = blockIdx.x * 4096;
    int cnt = min(4096, E - e0);
    if (cnt == 4096) {
        const int4* d4 = (const int4*)(dst + e0);
        for (int i = t; i < 1024; i += 256) {
            int4 v = d4[i];
            atomicAdd(&h[v.x >> BSHIFT], 1);
            atomicAdd(&h[v.y >> BSHIFT], 1);
            atomicAdd(&h[v.z >> BSHIFT], 1);
            atomicAdd(&h[v.w >> BSHIFT], 1);
        }
    } else {
        for (int i = t; i < cnt; i += 256)
            atomicAdd(&h[dst[e0 + i] >> BSHIFT], 1);
    }
    __syncthreads();
    for (int i = t; i < B; i += 256)
        if (h[i]) atomicAdd(&bucketcnt[i], h[i]);
}

// ---------------- bucket exclusive scan (block 0, 512-wide) + per-graph starts ----------------
__global__ __launch_bounds__(512) void k_bscan_starts(
        const int* __restrict__ cnt, int* __restrict__ bstart,
        int* __restrict__ bcursor, int B, int E,
        const int* __restrict__ batch, int n, int G,
        int* __restrict__ starts) {
    int t = threadIdx.x;          // blockDim = 512
    if (blockIdx.x == 0) {
        __shared__ int s[MAXB];
        int mine = (t < B) ? cnt[t] : 0;
        s[t] = mine;
        __syncthreads();
        for (int off = 1; off < MAXB; off <<= 1) {
            int add = (t >= off) ? s[t - off] : 0;
            __syncthreads();
            s[t] += add;
            __syncthreads();
        }
        if (t < B) { int ex = s[t] - mine; bstart[t] = ex; bcursor[t] = ex; }
        if (t == 0) bstart[B] = E;
    } else {
        int g = (blockIdx.x - 1) * 512 + t;
        if (g > G) return;
        if (g == G) { starts[G] = n; return; }
        int lo = 0, hi = n;
        while (lo < hi) { int mid = (lo + hi) >> 1; if (batch[mid] < g) lo = mid + 1; else hi = mid; }
        starts[g] = lo;
    }
}

// ---------------- phase 1: partition edges into bucket-contiguous packed array ----------------
__global__ __launch_bounds__(256) void k_part(const int* __restrict__ src,
                                              const int* __restrict__ dst, int E, int B,
                                              int* __restrict__ bcursor,
                                              unsigned* __restrict__ bpk) {
    __shared__ int4 s_src4[1024];
    __shared__ int4 s_dst4[1024];
    __shared__ int hist[MAXB];
    __shared__ int base[MAXB];
    int* s_src = (int*)s_src4;
    int* s_dst = (int*)s_dst4;
    int t = threadIdx.x;
    int e0 = blockIdx.x * 4096;
    int cnt = min(4096, E - e0);
    for (int i = t; i < MAXB; i += 256) hist[i] = 0;
    __syncthreads();
    if (cnt == 4096) {
        const int4* sv4 = (const int4*)(src + e0);
        const int4* dv4 = (const int4*)(dst + e0);
        for (int i = t; i < 1024; i += 256) {
            int4 a = sv4[i];
            int4 b = dv4[i];
            s_src4[i] = a;
            s_dst4[i] = b;
            atomicAdd(&hist[b.x >> BSHIFT], 1);
            atomicAdd(&hist[b.y >> BSHIFT], 1);
            atomicAdd(&hist[b.z >> BSHIFT], 1);
            atomicAdd(&hist[b.w >> BSHIFT], 1);
        }
    } else {
        for (int i = t; i < cnt; i += 256) {
            int d = dst[e0 + i];
            s_src[i] = src[e0 + i];
            s_dst[i] = d;
            atomicAdd(&hist[d >> BSHIFT], 1);
        }
    }
    __syncthreads();
    for (int i = t; i < B; i += 256) {
        int hh = hist[i];
        base[i] = hh ? atomicAdd(&bcursor[i], hh) : 0;
        hist[i] = 0;
    }
    __syncthreads();
    for (int i = t; i < cnt; i += 256) {
        int d = s_dst[i];
        int b = d >> BSHIFT;
        int off = atomicAdd(&hist[b], 1);
        bpk[base[b] + off] = ((unsigned)(d & (BSIZE - 1)) << 18) | (unsigned)s_src[i];
    }
}

// ---------------- phase 2: per-bucket CSR fill (512 thr, 1 node/thread) ----------------
__global__ __launch_bounds__(512) void k_fill3(const unsigned* __restrict__ bpk,
                                               const int* __restrict__ bstart,
                                               int n, int B,
                                               int* __restrict__ deg,
                                               int* __restrict__ rowstart,
                                               float* __restrict__ dis,
                                               int* __restrict__ ssrc) {
    __shared__ int cnt[BSIZE];     // 512
    __shared__ int s512[512];
    int b = blockIdx.x;
    int t = threadIdx.x;
    int s0 = bstart[b], s1 = bstart[b + 1];

    cnt[t] = 0;
    __syncthreads();
    // pass 1: count local degrees
    for (int i = s0 + t; i < s1; i += 512)
        atomicAdd(&cnt[bpk[i] >> 18], 1);
    __syncthreads();

    int c0 = cnt[t];
    s512[t] = c0;
    __syncthreads();
    for (int off = 1; off < 512; off <<= 1) {
        int add = (t >= off) ? s512[t - off] : 0;
        __syncthreads();
        s512[t] += add;
        __syncthreads();
    }
    int p0 = s0 + s512[t] - c0;

    int node0 = (b << BSHIFT) + t;
    if (node0 < n) {
        rowstart[node0] = p0;
        deg[node0] = c0;
        dis[node0] = rsqrtf((float)(c0 + 1));
    }
    cnt[t] = p0;
    __syncthreads();

    // pass 2: scatter via LDS cursors
    for (int i = s0 + t; i < s1; i += 512) {
        unsigned pk = bpk[i];
        int pos = atomicAdd(&cnt[pk >> 18], 1);
        ssrc[pos] = (int)(pk & 0x3FFFFu);
    }
}

// ---------------- layer-0 transform: gA[i,c] = dis[i]*(x[i,:20] @ W0[:,c]) ----------------
__global__ void k_t0(const float* __restrict__ x,
                     const float* __restrict__ W0,
                     const float* __restrict__ dis,
                     float* __restrict__ g, int n) {
    int t = blockIdx.x * blockDim.x + threadIdx.x;
    int i = t / 32, c = t % 32;
    if (i >= n) return;
    const float* xr = x + (size_t)i * 20;
    float a = 0.f;
#pragma unroll
    for (int f = 0; f < 20; ++f) a += xr[f] * W0[f * 32 + c];
    g[(size_t)i * 32 + c] = dis[i] * a;
}

// ---------------- CSR gather + finalize + fused next-layer transform ----------------
// MODE 0: epilogue computes gnext[i,0:32] = dis[i]*(h @ Wn[32x32])
// MODE 1: epilogue computes gnext[i]      = dis[i]*(h @ Wn[32])
template<int MODE>
__global__ __launch_bounds__(256) void k_gather32f(
    const int* __restrict__ rowstart, const int* __restrict__ deg,
    const int* __restrict__ ssrc, const float4* __restrict__ g4,
    const float* __restrict__ dis, const float* __restrict__ bias,
    const float* __restrict__ Wn,
    float* __restrict__ feat, int off,
    float* __restrict__ gnext, int n)
{
    __shared__ float hs[32][33];
    __shared__ float wsm[32 * 32];
    int t = blockIdx.x * 256 + threadIdx.x;
    int i = t >> 3, p = t & 7;
    bool valid = (i < n);

    if (MODE == 0) {
        for (int q = threadIdx.x; q < 1024; q += 256) wsm[q] = Wn[q];
    }

    float h0 = 0.f, h1 = 0.f, h2 = 0.f, h3 = 0.f;
    float sc = 0.f;
    if (valid) {
        int r0 = rowstart[i], d = deg[i];
        float4 acc = g4[(size_t)i * 8 + p];   // self-loop term
        int j = 0;
        for (; j + 4 <= d; j += 4) {
            int s0 = ssrc[r0 + j + 0];
            int s1 = ssrc[r0 + j + 1];
            int s2 = ssrc[r0 + j + 2];
            int s3 = ssrc[r0 + j + 3];
            float4 v0 = g4[(size_t)s0 * 8 + p];
            float4 v1 = g4[(size_t)s1 * 8 + p];
            float4 v2 = g4[(size_t)s2 * 8 + p];
            float4 v3 = g4[(size_t)s3 * 8 + p];
            acc.x += (v0.x + v1.x) + (v2.x + v3.x);
            acc.y += (v0.y + v1.y) + (v2.y + v3.y);
            acc.z += (v0.z + v1.z) + (v2.z + v3.z);
            acc.w += (v0.w + v1.w) + (v2.w + v3.w);
        }
        for (; j < d; ++j) {
            int s = ssrc[r0 + j];
            float4 v = g4[(size_t)s * 8 + p];
            acc.x += v.x; acc.y += v.y; acc.z += v.z; acc.w += v.w;
        }
        sc = dis[i];
        h0 = tanhf(sc * acc.x + bias[p * 4 + 0]);
        h1 = tanhf(sc * acc.y + bias[p * 4 + 1]);
        h2 = tanhf(sc * acc.z + bias[p * 4 + 2]);
        h3 = tanhf(sc * acc.w + bias[p * 4 + 3]);
        float* fr = feat + (size_t)i * D_TOT + off + p * 4;
        fr[0] = h0; fr[1] = h1; fr[2] = h2; fr[3] = h3;
    }

    int nl = threadIdx.x >> 3;
    hs[nl][p * 4 + 0] = h0;
    hs[nl][p * 4 + 1] = h1;
    hs[nl][p * 4 + 2] = h2;
    hs[nl][p * 4 + 3] = h3;
    __syncthreads();

    if (MODE == 0) {
        if (valid) {
            float a0 = 0.f, a1 = 0.f, a2 = 0.f, a3 = 0.f;
            const float* hr = hs[nl];
            int c0 = p * 4;
#pragma unroll
            for (int f = 0; f < 32; ++f) {
                float hv = hr[f];
                const float* wr = &wsm[f * 32 + c0];
                a0 += hv * wr[0];
                a1 += hv * wr[1];
                a2 += hv * wr[2];
                a3 += hv * wr[3];
            }
            float4* gn = (float4*)gnext;
            gn[(size_t)i * 8 + p] = make_float4(sc * a0, sc * a1, sc * a2, sc * a3);
        }
    } else {
        if (valid && p == 0) {
            float a = 0.f;
            const float* hr = hs[nl];
#pragma unroll
            for (int f = 0; f < 32; ++f) a += hr[f] * Wn[f];
            gnext[i] = sc * a;
        }
    }
}

// ---------------- fused layer-3 gather + sort-pool (bitonic) + CNN + MLP ----------------
constexpr int SORTN = 512;

__global__ __launch_bounds__(256) void k_cnn(
    const float* __restrict__ feat,
    const int* __restrict__ starts,
    const int* __restrict__ rowstart, const int* __restrict__ deg,
    const int* __restrict__ ssrc, const float* __restrict__ g1,
    const float* __restrict__ dis, const float* __restrict__ b3,
    const float* __restrict__ c1w, const float* __restrict__ c1b,
    const float* __restrict__ c2w, const float* __restrict__ c2b,
    const float* __restrict__ m1w, const float* __restrict__ m1b,
    const float* __restrict__ m2w, const float* __restrict__ m2b,
    float* __restrict__ out)
{
    int g = blockIdx.x;
    int tid = threadIdx.x;   // 256

    __shared__ unsigned long long keys[SORTN];
    __shared__ float vals[SORTN];
    __shared__ float pooled[K_POOL][D_TOT];
    __shared__ float y[16][K_POOL];
    __shared__ float z[16][15];
    __shared__ float u[352];
    __shared__ float pm[256];
    __shared__ float hid[32];

    int start = starts[g];
    int cnt = starts[g + 1] - start;
    if (cnt > SORTN) cnt = SORTN;
    int kk = cnt < K_POOL ? cnt : K_POOL;
    float bias3 = b3[0];

    // layer-3 gather: col-96 feature per node
    for (int il = tid; il < cnt; il += 256) {
        int i = start + il;
        int r0 = rowstart[i], d = deg[i];
        float acc = g1[i];
        for (int j = 0; j < d; ++j) acc += g1[ssrc[r0 + j]];
        vals[il] = tanhf(dis[i] * acc + bias3);
    }
    __syncthreads();

    int SN = (cnt <= 256) ? 256 : SORTN;

    for (int i = tid; i < SN; i += 256) {
        unsigned long long kv;
        if (i < cnt) {
            float v = vals[i];
            unsigned uo = __float_as_uint(v);
            uo ^= (unsigned)((int)uo >> 31) | 0x80000000u;
            kv = ((unsigned long long)(~uo) << 32) | (unsigned)i;
        } else {
            kv = 0xFFFFFFFFFFFFFFFFull;
        }
        keys[i] = kv;
    }
    __syncthreads();

    for (int sz = 2; sz <= SN; sz <<= 1) {
        for (int j = sz >> 1; j > 0; j >>= 1) {
            for (int q = tid; q < SN; q += 256) {
                int l = q ^ j;
                if (l > q) {
                    bool asc = ((q & sz) == 0);
                    unsigned long long a = keys[q], bb = keys[l];
                    if ((a > bb) == asc) { keys[q] = bb; keys[l] = a; }
                }
            }
            __syncthreads();
        }
    }

    float* pf = &pooled[0][0];
    for (int t = tid; t < K_POOL * D_TOT; t += 256) pf[t] = 0.f;
    __syncthreads();
    for (int t = tid; t < kk * 96; t += 256) {
        int r = t / 96, c = t - r * 96;
        int idx = (int)(keys[r] & 0xFFFFFFFFull);
        pooled[r][c] = feat[(size_t)(start + idx) * D_TOT + c];
    }
    for (int r = tid; r < kk; r += 256) {
        int idx = (int)(keys[r] & 0xFFFFFFFFull);
        pooled[r][96] = vals[idx];
    }
    __syncthreads();

    for (int t = tid; t < 16 * K_POOL; t += 256) {
        int o = t / K_POOL, p = t - o * K_POOL;
        float a = c1b[o];
        const float* w = c1w + o * D_TOT;
        const float* pr = &pooled[p][0];
#pragma unroll 1
        for (int c = 0; c < D_TOT; ++c) a += pr[c] * w[c];
        y[o][p] = fmaxf(a, 0.f);
    }
    __syncthreads();

    for (int t = tid; t < 16 * 15; t += 256) {
        int o = t / 15, p = t - o * 15;
        z[o][p] = fmaxf(y[o][2 * p], y[o][2 * p + 1]);
    }
    __syncthreads();

    for (int t = tid; t < 32 * 11; t += 256) {
        int q = t / 11, p = t - q * 11;
        float a = c2b[q];
        const float* w = c2w + q * 16 * 5;
#pragma unroll 1
        for (int c = 0; c < 16; ++c) {
#pragma unroll
            for (int j = 0; j < 5; ++j) a += z[c][p + j] * w[c * 5 + j];
        }
        u[t] = fmaxf(a, 0.f);
    }
    __syncthreads();

    {
        int grp = tid >> 5, o = tid & 31;
        float a = 0.f;
        int i0 = grp * 44;
#pragma unroll 1
        for (int i = i0; i < i0 + 44; ++i) a += u[i] * m1w[i * 32 + o];
        pm[tid] = a;
    }
    __syncthreads();
    if (tid < 32) {
        float a = m1b[tid];
#pragma unroll
        for (int gg = 0; gg < 8; ++gg) a += pm[tid + 32 * gg];
        hid[tid] = fmaxf(a, 0.f);
    }
    __syncthreads();

    if (tid == 0) {
        float a = m2b[0];
#pragma unroll
        for (int m = 0; m < 32; ++m) a += hid[m] * m2w[m];
        out[g] = a;
    }
}

// ---------------- launch ----------------
extern "C" void kernel_launch(void* const* d_in, const int* in_sizes, int n_in,
                              void* d_out, int out_size, void* d_ws, size_t ws_size,
                              hipStream_t stream) {
    const float* x    = (const float*)d_in[0];
    const int*   ei   = (const int*)d_in[1];
    const int*   batch= (const int*)d_in[2];
    const float* W0   = (const float*)d_in[3];
    const float* b0   = (const float*)d_in[4];
    const float* W1   = (const float*)d_in[5];
    const float* b1   = (const float*)d_in[6];
    const float* W2   = (const float*)d_in[7];
    const float* b2   = (const float*)d_in[8];
    const float* W3   = (const float*)d_in[9];
    const float* b3   = (const float*)d_in[10];
    const float* c1w  = (const float*)d_in[11];
    const float* c1b  = (const float*)d_in[12];
    const float* c2w  = (const float*)d_in[13];
    const float* c2b  = (const float*)d_in[14];
    const float* m1w  = (const float*)d_in[15];
    const float* m1b  = (const float*)d_in[16];
    const float* m2w  = (const float*)d_in[17];
    const float* m2b  = (const float*)d_in[18];

    const int n = in_sizes[0] / 20;
    const int E = in_sizes[1] / 2;
    const int G = out_size;
    const int* srcv = ei;
    const int* dstv = ei + E;
    const int B = (n + BSIZE - 1) >> BSHIFT;
    const int nE4 = (E + 4095) / 4096;

    char* ws = (char*)d_ws;
    float* feat    = (float*)ws;  ws += (size_t)n * D_TOT * sizeof(float);
    float* gA      = (float*)ws;  ws += (size_t)n * 32 * sizeof(float);
    float* gB      = (float*)ws;  ws += (size_t)n * 32 * sizeof(float);
    int*   ssrc    = (int*)ws;    ws += (size_t)E * sizeof(int);
    unsigned* bpk  = (unsigned*)ws; ws += (size_t)E * sizeof(unsigned);
    int*   rowstart= (int*)ws;    ws += (size_t)n * sizeof(int);
    int*   deg     = (int*)ws;    ws += (size_t)n * sizeof(int);
    float* dis     = (float*)ws;  ws += (size_t)n * sizeof(float);
    int*   startsb = (int*)ws;    ws += (size_t)(G + 1) * sizeof(int);
    int*   bucketcnt=(int*)ws;    ws += (size_t)MAXB * sizeof(int);
    int*   bstart  = (int*)ws;    ws += (size_t)(MAXB + 1) * sizeof(int);
    int*   bcursor = (int*)ws;    ws += (size_t)MAXB * sizeof(int);
    float* g1      = (float*)bpk;  // alias: bpk dead after CSR build

    hipMemsetAsync(bucketcnt, 0, (size_t)MAXB * sizeof(int), stream);

    // CSR build (bucketed, no global data atomics; reused by all 4 layers)
    k_bcount<<<nE4, 256, 0, stream>>>(dstv, E, bucketcnt, B);
    const int nSB = (G + 1 + 511) / 512;
    k_bscan_starts<<<1 + nSB, 512, 0, stream>>>(bucketcnt, bstart, bcursor, B, E,
                                                batch, n, G, startsb);
    k_part<<<nE4, 256, 0, stream>>>(srcv, dstv, E, B, bcursor, bpk);
    k_fill3<<<B, 512, 0, stream>>>(bpk, bstart, n, B, deg, rowstart, dis, ssrc);

    // layer-0 transform (needs dis)
    k_t0<<<(n * 32 + 255) / 256, 256, 0, stream>>>(x, W0, dis, gA, n);

    const int nb8 = (n * 8 + 255) / 256;
    // layer 0 gather + fused transform W1 -> gB
    k_gather32f<0><<<nb8, 256, 0, stream>>>(rowstart, deg, ssrc, (const float4*)gA, dis, b0, W1, feat, 0, gB, n);
    // layer 1 gather + fused transform W2 -> gA
    k_gather32f<0><<<nb8, 256, 0, stream>>>(rowstart, deg, ssrc, (const float4*)gB, dis, b1, W2, feat, 32, gA, n);
    // layer 2 gather + fused scalar transform W3 -> g1
    k_gather32f<1><<<nb8, 256, 0, stream>>>(rowstart, deg, ssrc, (const float4*)gA, dis, b2, W3, feat, 64, g1, n);

    // fused layer-3 gather + sort-pool + CNN + MLP
    k_cnn<<<G, 256, 0, stream>>>(feat, startsb, rowstart, deg, ssrc, g1, dis, b3,
                                 c1w, c1b, c2w, c2b, m1w, m1b, m2w, m2b,
                                 (float*)d_out);
}

// Round 12
// 427.375 us; speedup vs baseline: 1.5292x; 1.0327x over previous
//
#include <hip/hip_runtime.h>
#include <math.h>

constexpr int D_TOT = 97;
constexpr int K_POOL = 30;
constexpr int BSHIFT = 9;                  // 512 nodes per bucket
constexpr int BSIZE  = 1 << BSHIFT;
constexpr int MAXB   = 512;                // max buckets (n < 262144)

// ---------------- bucket histogram (LDS-aggregated, int4 loads) ----------------
__global__ __launch_bounds__(256) void k_bcount(const int* __restrict__ dst, int E,
                                                int* __restrict__ bucketcnt, int B) {
    __shared__ int h[MAXB];
    int t = threadIdx.x;
    for (int i = t; i < MAXB; i += 256) h[i] = 0;
    __syncthreads();
    int e0 = blockIdx.x * 4096;
    int cnt = min(4096, E - e0);
    if (cnt == 4096) {
        const int4* d4 = (const int4*)(dst + e0);
        for (int i = t; i < 1024; i += 256) {
            int4 v = d4[i];
            atomicAdd(&h[v.x >> BSHIFT], 1);
            atomicAdd(&h[v.y >> BSHIFT], 1);
            atomicAdd(&h[v.z >> BSHIFT], 1);
            atomicAdd(&h[v.w >> BSHIFT], 1);
        }
    } else {
        for (int i = t; i < cnt; i += 256)
            atomicAdd(&h[dst[e0 + i] >> BSHIFT], 1);
    }
    __syncthreads();
    for (int i = t; i < B; i += 256)
        if (h[i]) atomicAdd(&bucketcnt[i], h[i]);
}

// ---------------- bucket exclusive scan (block 0, 512-wide) + per-graph starts ----------------
__global__ __launch_bounds__(512) void k_bscan_starts(
        const int* __restrict__ cnt, int* __restrict__ bstart,
        int* __restrict__ bcursor, int B, int E,
        const int* __restrict__ batch, int n, int G,
        int* __restrict__ starts) {
    int t = threadIdx.x;          // blockDim = 512
    if (blockIdx.x == 0) {
        __shared__ int s[MAXB];
        int mine = (t < B) ? cnt[t] : 0;
        s[t] = mine;
        __syncthreads();
        for (int off = 1; off < MAXB; off <<= 1) {
            int add = (t >= off) ? s[t - off] : 0;
            __syncthreads();
            s[t] += add;
            __syncthreads();
        }
        if (t < B) { int ex = s[t] - mine; bstart[t] = ex; bcursor[t] = ex; }
        if (t == 0) bstart[B] = E;
    } else {
        int g = (blockIdx.x - 1) * 512 + t;
        if (g > G) return;
        if (g == G) { starts[G] = n; return; }
        int lo = 0, hi = n;
        while (lo < hi) { int mid = (lo + hi) >> 1; if (batch[mid] < g) lo = mid + 1; else hi = mid; }
        starts[g] = lo;
    }
}

// ---------------- phase 1: partition edges into bucket-contiguous packed array ----------------
__global__ __launch_bounds__(256) void k_part(const int* __restrict__ src,
                                              const int* __restrict__ dst, int E, int B,
                                              int* __restrict__ bcursor,
                                              unsigned* __restrict__ bpk) {
    __shared__ int4 s_src4[1024];
    __shared__ int4 s_dst4[1024];
    __shared__ int hist[MAXB];
    __shared__ int base[MAXB];
    int* s_src = (int*)s_src4;
    int* s_dst = (int*)s_dst4;
    int t = threadIdx.x;
    int e0 = blockIdx.x * 4096;
    int cnt = min(4096, E - e0);
    for (int i = t; i < MAXB; i += 256) hist[i] = 0;
    __syncthreads();
    if (cnt == 4096) {
        const int4* sv4 = (const int4*)(src + e0);
        const int4* dv4 = (const int4*)(dst + e0);
        for (int i = t; i < 1024; i += 256) {
            int4 a = sv4[i];
            int4 b = dv4[i];
            s_src4[i] = a;
            s_dst4[i] = b;
            atomicAdd(&hist[b.x >> BSHIFT], 1);
            atomicAdd(&hist[b.y >> BSHIFT], 1);
            atomicAdd(&hist[b.z >> BSHIFT], 1);
            atomicAdd(&hist[b.w >> BSHIFT], 1);
        }
    } else {
        for (int i = t; i < cnt; i += 256) {
            int d = dst[e0 + i];
            s_src[i] = src[e0 + i];
            s_dst[i] = d;
            atomicAdd(&hist[d >> BSHIFT], 1);
        }
    }
    __syncthreads();
    for (int i = t; i < B; i += 256) {
        int hh = hist[i];
        base[i] = hh ? atomicAdd(&bcursor[i], hh) : 0;
        hist[i] = 0;
    }
    __syncthreads();
    for (int i = t; i < cnt; i += 256) {
        int d = s_dst[i];
        int b = d >> BSHIFT;
        int off = atomicAdd(&hist[b], 1);
        bpk[base[b] + off] = ((unsigned)(d & (BSIZE - 1)) << 18) | (unsigned)s_src[i];
    }
}

// ---------------- phase 2: per-bucket CSR fill (512 thr, 1 node/thread) + fused layer-0 transform ----------------
__global__ __launch_bounds__(512) void k_fill3(const unsigned* __restrict__ bpk,
                                               const int* __restrict__ bstart,
                                               int n, int B,
                                               int* __restrict__ deg,
                                               int* __restrict__ rowstart,
                                               float* __restrict__ dis,
                                               int* __restrict__ ssrc,
                                               const float* __restrict__ x,
                                               const float* __restrict__ W0,
                                               float4* __restrict__ gA4) {
    __shared__ int cnt[BSIZE];     // 512
    __shared__ int s512[512];
    __shared__ float w0s[20 * 32];
    int b = blockIdx.x;
    int t = threadIdx.x;
    int s0 = bstart[b], s1 = bstart[b + 1];

    cnt[t] = 0;
    if (t < 320) { w0s[t] = W0[t]; w0s[t + 320] = W0[t + 320]; }
    __syncthreads();
    // pass 1: count local degrees
    for (int i = s0 + t; i < s1; i += 512)
        atomicAdd(&cnt[bpk[i] >> 18], 1);
    __syncthreads();

    int c0 = cnt[t];
    s512[t] = c0;
    __syncthreads();
    for (int off = 1; off < 512; off <<= 1) {
        int add = (t >= off) ? s512[t - off] : 0;
        __syncthreads();
        s512[t] += add;
        __syncthreads();
    }
    int p0 = s0 + s512[t] - c0;

    int node0 = (b << BSHIFT) + t;
    float d0 = rsqrtf((float)(c0 + 1));
    if (node0 < n) {
        rowstart[node0] = p0;
        deg[node0] = c0;
        dis[node0] = d0;
    }
    cnt[t] = p0;
    __syncthreads();

    // pass 2: scatter via LDS cursors
    for (int i = s0 + t; i < s1; i += 512) {
        unsigned pk = bpk[i];
        int pos = atomicAdd(&cnt[pk >> 18], 1);
        ssrc[pos] = (int)(pk & 0x3FFFFu);
    }

    // fused layer-0 transform: this thread's node, all 32 cols in registers
    if (node0 < n) {
        float xr[20];
        const float* xp = x + (size_t)node0 * 20;
#pragma unroll
        for (int f = 0; f < 20; ++f) xr[f] = xp[f];
#pragma unroll
        for (int q = 0; q < 8; ++q) {
            int c = q * 4;
            float a0 = 0.f, a1 = 0.f, a2 = 0.f, a3 = 0.f;
#pragma unroll
            for (int f = 0; f < 20; ++f) {
                float xv = xr[f];
                const float* wr = &w0s[f * 32 + c];
                a0 += xv * wr[0];
                a1 += xv * wr[1];
                a2 += xv * wr[2];
                a3 += xv * wr[3];
            }
            gA4[(size_t)node0 * 8 + q] = make_float4(d0 * a0, d0 * a1, d0 * a2, d0 * a3);
        }
    }
}

// ---------------- CSR gather + finalize + fused next-layer transform ----------------
// MODE 0: epilogue computes gnext[i,0:32] = dis[i]*(h @ Wn[32x32])
// MODE 1: epilogue computes gnext[i]      = dis[i]*(h @ Wn[32])
template<int MODE>
__global__ __launch_bounds__(256) void k_gather32f(
    const int* __restrict__ rowstart, const int* __restrict__ deg,
    const int* __restrict__ ssrc, const float4* __restrict__ g4,
    const float* __restrict__ dis, const float* __restrict__ bias,
    const float* __restrict__ Wn,
    float* __restrict__ feat, int off,
    float* __restrict__ gnext, int n)
{
    __shared__ float hs[32][33];
    __shared__ float wsm[32 * 32];
    int t = blockIdx.x * 256 + threadIdx.x;
    int i = t >> 3, p = t & 7;
    bool valid = (i < n);

    if (MODE == 0) {
        for (int q = threadIdx.x; q < 1024; q += 256) wsm[q] = Wn[q];
    }

    float h0 = 0.f, h1 = 0.f, h2 = 0.f, h3 = 0.f;
    float sc = 0.f;
    if (valid) {
        int r0 = rowstart[i], d = deg[i];
        float4 acc = g4[(size_t)i * 8 + p];   // self-loop term
        int j = 0;
        for (; j + 4 <= d; j += 4) {
            int s0 = ssrc[r0 + j + 0];
            int s1 = ssrc[r0 + j + 1];
            int s2 = ssrc[r0 + j + 2];
            int s3 = ssrc[r0 + j + 3];
            float4 v0 = g4[(size_t)s0 * 8 + p];
            float4 v1 = g4[(size_t)s1 * 8 + p];
            float4 v2 = g4[(size_t)s2 * 8 + p];
            float4 v3 = g4[(size_t)s3 * 8 + p];
            acc.x += (v0.x + v1.x) + (v2.x + v3.x);
            acc.y += (v0.y + v1.y) + (v2.y + v3.y);
            acc.z += (v0.z + v1.z) + (v2.z + v3.z);
            acc.w += (v0.w + v1.w) + (v2.w + v3.w);
        }
        for (; j < d; ++j) {
            int s = ssrc[r0 + j];
            float4 v = g4[(size_t)s * 8 + p];
            acc.x += v.x; acc.y += v.y; acc.z += v.z; acc.w += v.w;
        }
        sc = dis[i];
        h0 = tanhf(sc * acc.x + bias[p * 4 + 0]);
        h1 = tanhf(sc * acc.y + bias[p * 4 + 1]);
        h2 = tanhf(sc * acc.z + bias[p * 4 + 2]);
        h3 = tanhf(sc * acc.w + bias[p * 4 + 3]);
        float* fr = feat + (size_t)i * D_TOT + off + p * 4;
        fr[0] = h0; fr[1] = h1; fr[2] = h2; fr[3] = h3;
    }

    int nl = threadIdx.x >> 3;
    hs[nl][p * 4 + 0] = h0;
    hs[nl][p * 4 + 1] = h1;
    hs[nl][p * 4 + 2] = h2;
    hs[nl][p * 4 + 3] = h3;
    __syncthreads();

    if (MODE == 0) {
        if (valid) {
            float a0 = 0.f, a1 = 0.f, a2 = 0.f, a3 = 0.f;
            const float* hr = hs[nl];
            int c0 = p * 4;
#pragma unroll
            for (int f = 0; f < 32; ++f) {
                float hv = hr[f];
                const float* wr = &wsm[f * 32 + c0];
                a0 += hv * wr[0];
                a1 += hv * wr[1];
                a2 += hv * wr[2];
                a3 += hv * wr[3];
            }
            float4* gn = (float4*)gnext;
            gn[(size_t)i * 8 + p] = make_float4(sc * a0, sc * a1, sc * a2, sc * a3);
        }
    } else {
        if (valid && p == 0) {
            float a = 0.f;
            const float* hr = hs[nl];
#pragma unroll
            for (int f = 0; f < 32; ++f) a += hr[f] * Wn[f];
            gnext[i] = sc * a;
        }
    }
}

// ---------------- fused layer-3 gather + sort-pool (bitonic) + CNN + MLP ----------------
constexpr int SORTN = 512;

__global__ __launch_bounds__(256) void k_cnn(
    const float* __restrict__ feat,
    const int* __restrict__ starts,
    const int* __restrict__ rowstart, const int* __restrict__ deg,
    const int* __restrict__ ssrc, const float* __restrict__ g1,
    const float* __restrict__ dis, const float* __restrict__ b3,
    const float* __restrict__ c1w, const float* __restrict__ c1b,
    const float* __restrict__ c2w, const float* __restrict__ c2b,
    const float* __restrict__ m1w, const float* __restrict__ m1b,
    const float* __restrict__ m2w, const float* __restrict__ m2b,
    float* __restrict__ out)
{
    int g = blockIdx.x;
    int tid = threadIdx.x;   // 256

    __shared__ unsigned long long keys[SORTN];
    __shared__ float vals[SORTN];
    __shared__ float pooled[K_POOL][D_TOT];
    __shared__ float y[16][K_POOL];
    __shared__ float z[16][15];
    __shared__ float u[352];
    __shared__ float pm[256];
    __shared__ float hid[32];

    int start = starts[g];
    int cnt = starts[g + 1] - start;
    if (cnt > SORTN) cnt = SORTN;
    int kk = cnt < K_POOL ? cnt : K_POOL;
    float bias3 = b3[0];

    // layer-3 gather: col-96 feature per node
    for (int il = tid; il < cnt; il += 256) {
        int i = start + il;
        int r0 = rowstart[i], d = deg[i];
        float acc = g1[i];
        for (int j = 0; j < d; ++j) acc += g1[ssrc[r0 + j]];
        vals[il] = tanhf(dis[i] * acc + bias3);
    }
    __syncthreads();

    int SN = (cnt <= 256) ? 256 : SORTN;

    for (int i = tid; i < SN; i += 256) {
        unsigned long long kv;
        if (i < cnt) {
            float v = vals[i];
            unsigned uo = __float_as_uint(v);
            uo ^= (unsigned)((int)uo >> 31) | 0x80000000u;
            kv = ((unsigned long long)(~uo) << 32) | (unsigned)i;
        } else {
            kv = 0xFFFFFFFFFFFFFFFFull;
        }
        keys[i] = kv;
    }
    __syncthreads();

    for (int sz = 2; sz <= SN; sz <<= 1) {
        for (int j = sz >> 1; j > 0; j >>= 1) {
            for (int q = tid; q < SN; q += 256) {
                int l = q ^ j;
                if (l > q) {
                    bool asc = ((q & sz) == 0);
                    unsigned long long a = keys[q], bb = keys[l];
                    if ((a > bb) == asc) { keys[q] = bb; keys[l] = a; }
                }
            }
            __syncthreads();
        }
    }

    float* pf = &pooled[0][0];
    for (int t = tid; t < K_POOL * D_TOT; t += 256) pf[t] = 0.f;
    __syncthreads();
    for (int t = tid; t < kk * 96; t += 256) {
        int r = t / 96, c = t - r * 96;
        int idx = (int)(keys[r] & 0xFFFFFFFFull);
        pooled[r][c] = feat[(size_t)(start + idx) * D_TOT + c];
    }
    for (int r = tid; r < kk; r += 256) {
        int idx = (int)(keys[r] & 0xFFFFFFFFull);
        pooled[r][96] = vals[idx];
    }
    __syncthreads();

    for (int t = tid; t < 16 * K_POOL; t += 256) {
        int o = t / K_POOL, p = t - o * K_POOL;
        float a = c1b[o];
        const float* w = c1w + o * D_TOT;
        const float* pr = &pooled[p][0];
#pragma unroll 1
        for (int c = 0; c < D_TOT; ++c) a += pr[c] * w[c];
        y[o][p] = fmaxf(a, 0.f);
    }
    __syncthreads();

    for (int t = tid; t < 16 * 15; t += 256) {
        int o = t / 15, p = t - o * 15;
        z[o][p] = fmaxf(y[o][2 * p], y[o][2 * p + 1]);
    }
    __syncthreads();

    for (int t = tid; t < 32 * 11; t += 256) {
        int q = t / 11, p = t - q * 11;
        float a = c2b[q];
        const float* w = c2w + q * 16 * 5;
#pragma unroll 1
        for (int c = 0; c < 16; ++c) {
#pragma unroll
            for (int j = 0; j < 5; ++j) a += z[c][p + j] * w[c * 5 + j];
        }
        u[t] = fmaxf(a, 0.f);
    }
    __syncthreads();

    {
        int grp = tid >> 5, o = tid & 31;
        float a = 0.f;
        int i0 = grp * 44;
#pragma unroll 1
        for (int i = i0; i < i0 + 44; ++i) a += u[i] * m1w[i * 32 + o];
        pm[tid] = a;
    }
    __syncthreads();
    if (tid < 32) {
        float a = m1b[tid];
#pragma unroll
        for (int gg = 0; gg < 8; ++gg) a += pm[tid + 32 * gg];
        hid[tid] = fmaxf(a, 0.f);
    }
    __syncthreads();

    if (tid == 0) {
        float a = m2b[0];
#pragma unroll
        for (int m = 0; m < 32; ++m) a += hid[m] * m2w[m];
        out[g] = a;
    }
}

// ---------------- launch ----------------
extern "C" void kernel_launch(void* const* d_in, const int* in_sizes, int n_in,
                              void* d_out, int out_size, void* d_ws, size_t ws_size,
                              hipStream_t stream) {
    const float* x    = (const float*)d_in[0];
    const int*   ei   = (const int*)d_in[1];
    const int*   batch= (const int*)d_in[2];
    const float* W0   = (const float*)d_in[3];
    const float* b0   = (const float*)d_in[4];
    const float* W1   = (const float*)d_in[5];
    const float* b1   = (const float*)d_in[6];
    const float* W2   = (const float*)d_in[7];
    const float* b2   = (const float*)d_in[8];
    const float* W3   = (const float*)d_in[9];
    const float* b3   = (const float*)d_in[10];
    const float* c1w  = (const float*)d_in[11];
    const float* c1b  = (const float*)d_in[12];
    const float* c2w  = (const float*)d_in[13];
    const float* c2b  = (const float*)d_in[14];
    const float* m1w  = (const float*)d_in[15];
    const float* m1b  = (const float*)d_in[16];
    const float* m2w  = (const float*)d_in[17];
    const float* m2b  = (const float*)d_in[18];

    const int n = in_sizes[0] / 20;
    const int E = in_sizes[1] / 2;
    const int G = out_size;
    const int* srcv = ei;
    const int* dstv = ei + E;
    const int B = (n + BSIZE - 1) >> BSHIFT;
    const int nE4 = (E + 4095) / 4096;

    char* ws = (char*)d_ws;
    float* feat    = (float*)ws;  ws += (size_t)n * D_TOT * sizeof(float);
    float* gA      = (float*)ws;  ws += (size_t)n * 32 * sizeof(float);
    float* gB      = (float*)ws;  ws += (size_t)n * 32 * sizeof(float);
    int*   ssrc    = (int*)ws;    ws += (size_t)E * sizeof(int);
    unsigned* bpk  = (unsigned*)ws; ws += (size_t)E * sizeof(unsigned);
    int*   rowstart= (int*)ws;    ws += (size_t)n * sizeof(int);
    int*   deg     = (int*)ws;    ws += (size_t)n * sizeof(int);
    float* dis     = (float*)ws;  ws += (size_t)n * sizeof(float);
    int*   startsb = (int*)ws;    ws += (size_t)(G + 1) * sizeof(int);
    int*   bucketcnt=(int*)ws;    ws += (size_t)MAXB * sizeof(int);
    int*   bstart  = (int*)ws;    ws += (size_t)(MAXB + 1) * sizeof(int);
    int*   bcursor = (int*)ws;    ws += (size_t)MAXB * sizeof(int);
    float* g1      = (float*)bpk;  // alias: bpk dead after CSR build

    hipMemsetAsync(bucketcnt, 0, (size_t)MAXB * sizeof(int), stream);

    // CSR build (bucketed, no global data atomics; reused by all 4 layers)
    k_bcount<<<nE4, 256, 0, stream>>>(dstv, E, bucketcnt, B);
    const int nSB = (G + 1 + 511) / 512;
    k_bscan_starts<<<1 + nSB, 512, 0, stream>>>(bucketcnt, bstart, bcursor, B, E,
                                                batch, n, G, startsb);
    k_part<<<nE4, 256, 0, stream>>>(srcv, dstv, E, B, bcursor, bpk);
    // CSR fill + fused layer-0 transform (dis computed in-register)
    k_fill3<<<B, 512, 0, stream>>>(bpk, bstart, n, B, deg, rowstart, dis, ssrc,
                                   x, W0, (float4*)gA);

    const int nb8 = (n * 8 + 255) / 256;
    // layer 0 gather + fused transform W1 -> gB
    k_gather32f<0><<<nb8, 256, 0, stream>>>(rowstart, deg, ssrc, (const float4*)gA, dis, b0, W1, feat, 0, gB, n);
    // layer 1 gather + fused transform W2 -> gA
    k_gather32f<0><<<nb8, 256, 0, stream>>>(rowstart, deg, ssrc, (const float4*)gB, dis, b1, W2, feat, 32, gA, n);
    // layer 2 gather + fused scalar transform W3 -> g1
    k_gather32f<1><<<nb8, 256, 0, stream>>>(rowstart, deg, ssrc, (const float4*)gA, dis, b2, W3, feat, 64, g1, n);

    // fused layer-3 gather + sort-pool + CNN + MLP
    k_cnn<<<G, 256, 0, stream>>>(feat, startsb, rowstart, deg, ssrc, g1, dis, b3,
                                 c1w, c1b, c2w, c2b, m1w, m1b, m2w, m2b,
                                 (float*)d_out);
}